// Round 17
// baseline (1768.610 us; speedup 1.0000x reference)
//
#include <hip/hip_runtime.h>

// ---------------------------------------------------------------------------
// Transformer decoder fwd, bf16-MFMA compute, fp32 residual stream in d_out.
// L=8 B=4 S=1024 D=1024 H=16 dh=64 FC=4096. Threshold 0.1 allows bf16 GEMMs.
// QKV/W1: 256^2 ring GEMM (BK=32, 8-slot ring, stage t+3, counted vmcnt(8),
//   2-phase per-K-tile interleave: {reads+stage | barrier | 16 MFMA} x2).
// Wo/W2: gemm4k (128x64, 3+3-slot ring, vmcnt(6)). LN: wave/row.
// Attn: v9 (LDS-staged K/V, 32x32 MFMA, swapped QK^T/PV, per-lane softmax).
// Weight prep: ONE kernel/layer.
// ---------------------------------------------------------------------------

typedef __bf16 bf16x8 __attribute__((ext_vector_type(8)));
typedef float  f32x4  __attribute__((ext_vector_type(4)));
typedef float  f32x16 __attribute__((ext_vector_type(16)));
typedef unsigned int u32x4 __attribute__((ext_vector_type(4)));

#define DEV static __device__ __forceinline__

DEV unsigned short f2bf(float x) {
  unsigned u = __builtin_bit_cast(unsigned int, x);
  u += 0x7fffu + ((u >> 16) & 1u);          // RNE
  return (unsigned short)(u >> 16);
}

DEV unsigned int pack2bf(float lo, float hi) {
  return (unsigned int)f2bf(lo) | ((unsigned int)f2bf(hi) << 16);
}

DEV f32x4 mfma16(bf16x8 a, bf16x8 b, f32x4 c) {
  return __builtin_amdgcn_mfma_f32_16x16x32_bf16(a, b, c, 0, 0, 0);
}

DEV f32x16 mfma32(bf16x8 a, bf16x8 b, f32x16 c) {
  return __builtin_amdgcn_mfma_f32_32x32x16_bf16(a, b, c, 0, 0, 0);
}

DEV bf16x8 ldb8(const unsigned short* p) {
  return *reinterpret_cast<const bf16x8*>(p);
}

DEV void gload_lds16(const unsigned short* g, unsigned short* l) {
  __builtin_amdgcn_global_load_lds(
      (const __attribute__((address_space(1))) void*)g,
      (__attribute__((address_space(3))) void*)l, 16, 0, 0);
}

// ---------------------------------------------------------------------------
// prep_layer: ALL weight prep for one layer in one dispatch.
// ---------------------------------------------------------------------------
__global__ __launch_bounds__(256) void prep_layer(
    const float* __restrict__ Wq, const float* __restrict__ Wk,
    const float* __restrict__ Wv, const float* __restrict__ Wo,
    const float* __restrict__ W1, const float* __restrict__ W2,
    const float* __restrict__ bq, const float* __restrict__ bk,
    const float* __restrict__ bv,
    unsigned short* __restrict__ Wqkv_t, unsigned short* __restrict__ Wo_t,
    unsigned short* __restrict__ W1_t, unsigned short* __restrict__ W2_t,
    float* __restrict__ bqkv) {
  const int bid = blockIdx.x;
  const int t = threadIdx.x;
  if (bid >= 12288) {                        // bias pack (12 x 256 = 3072)
    const int i = (bid - 12288) * 256 + t;
    bqkv[i] = (i < 1024) ? bq[i] : (i < 2048 ? bk[i - 1024] : bv[i - 2048]);
    return;
  }
  const float* src;
  unsigned short* dst;
  int kt, nt, srcStride, dstStride;
  if (bid < 4096) {
    const int z = bid >> 10, tile = bid & 1023;
    src = (z == 0) ? Wq : (z == 1) ? Wk : (z == 2) ? Wv : Wo;
    dst = (z == 3) ? Wo_t : (Wqkv_t + (size_t)z * 1024 * 1024);
    kt = tile >> 5; nt = tile & 31; srcStride = 1024; dstStride = 1024;
  } else if (bid < 8192) {
    const int tile = bid - 4096;
    src = W1; dst = W1_t;
    kt = tile >> 7; nt = tile & 127; srcStride = 4096; dstStride = 1024;
  } else {
    const int tile = bid - 8192;
    src = W2; dst = W2_t;
    kt = tile >> 5; nt = tile & 31; srcStride = 1024; dstStride = 4096;
  }
  __shared__ float ts[32][33];
  const int r = t >> 3, c4 = (t & 7) << 2;
  const int k = kt * 32 + r, n0 = nt * 32 + c4;
  const float4 v = *reinterpret_cast<const float4*>(src + (size_t)k * srcStride + n0);
  ts[r][c4] = v.x; ts[r][c4 + 1] = v.y; ts[r][c4 + 2] = v.z; ts[r][c4 + 3] = v.w;
  __syncthreads();
  const int n = nt * 32 + r, k0 = kt * 32 + c4;
  ushort4 o;
  o.x = f2bf(ts[c4][r]);     o.y = f2bf(ts[c4 + 1][r]);
  o.z = f2bf(ts[c4 + 2][r]); o.w = f2bf(ts[c4 + 3][r]);
  *reinterpret_cast<ushort4*>(dst + (size_t)n * dstStride + k0) = o;
}

// ---------------------------------------------------------------------------
// LayerNorm v2: ONE WAVE PER ROW, 4 rows/block, grid = 1024.
// ---------------------------------------------------------------------------
template <int OUTF32>
__global__ __launch_bounds__(256) void ln_kernel(
    const float* x, const float* __restrict__ gam,
    const float* __restrict__ bet, void* out) {
  const int t = threadIdx.x, wave = t >> 6, lane = t & 63;
  const int row = blockIdx.x * 4 + wave;
  const float* xr = x + (size_t)row * 1024;
  float4 v[4];
  float s = 0.f, ss = 0.f;
  #pragma unroll
  for (int k = 0; k < 4; ++k) {
    v[k] = *reinterpret_cast<const float4*>(xr + k * 256 + lane * 4);
    s  += v[k].x + v[k].y + v[k].z + v[k].w;
    ss += v[k].x * v[k].x + v[k].y * v[k].y + v[k].z * v[k].z + v[k].w * v[k].w;
  }
  #pragma unroll
  for (int m = 1; m <= 32; m <<= 1) { s += __shfl_xor(s, m); ss += __shfl_xor(ss, m); }
  const float mean = s * (1.0f / 1024.0f);
  const float var  = ss * (1.0f / 1024.0f) - mean * mean;
  const float rstd = rsqrtf(var + 1e-5f);
  #pragma unroll
  for (int k = 0; k < 4; ++k) {
    const float4 g  = *reinterpret_cast<const float4*>(gam + k * 256 + lane * 4);
    const float4 bb = *reinterpret_cast<const float4*>(bet + k * 256 + lane * 4);
    const float y0 = (v[k].x - mean) * rstd * g.x + bb.x;
    const float y1 = (v[k].y - mean) * rstd * g.y + bb.y;
    const float y2 = (v[k].z - mean) * rstd * g.z + bb.z;
    const float y3 = (v[k].w - mean) * rstd * g.w + bb.w;
    if (OUTF32) {
      float4 o; o.x = y0; o.y = y1; o.z = y2; o.w = y3;
      *reinterpret_cast<float4*>((float*)out + (size_t)row * 1024 + k * 256 + lane * 4) = o;
    } else {
      ushort4 o; o.x = f2bf(y0); o.y = f2bf(y1); o.z = f2bf(y2); o.w = f2bf(y3);
      *reinterpret_cast<ushort4*>((unsigned short*)out + (size_t)row * 1024 + k * 256 + lane * 4) = o;
    }
  }
}

// ---------------------------------------------------------------------------
// gemm8r: 256x256 tile, BK=32, 512 thr = 8 waves. 8-slot ring (128KB);
// stage t+3; counted vmcnt(8); swizzle slot^=(row>>1)&3.
// 2-phase per-K-tile interleave: each phase = {ds_reads + stage-issue |
// raw barrier | lgkmcnt(0)+sched_barrier | 16 MFMA | barrier}.
// MODE 1: bias+gelu. MODE 3: QKV split (V -> vT transposed).
// ---------------------------------------------------------------------------
template <int MODE>
__global__ __launch_bounds__(512) void gemm8r(
    const unsigned short* __restrict__ A, const unsigned short* __restrict__ Bt,
    const float* __restrict__ bias, unsigned short* __restrict__ outb,
    unsigned short* __restrict__ vT, int N, int K) {
  __shared__ __attribute__((aligned(16))) unsigned short lds[8 * 8192]; // 128KB
  const int t = threadIdx.x, wave = t >> 6, lane = t & 63;
  const int wm = wave >> 2, wn = wave & 3;
  const int rl15 = lane & 15;

  const int nbn = N >> 8;
  const int qq  = gridDim.x >> 3;
  const int swz = (blockIdx.x & 7) * qq + (blockIdx.x >> 3);
  const int m0 = (swz / nbn) << 8, n0 = (swz % nbn) << 8;

  const unsigned short* aG = A  + (size_t)m0 * K;
  const unsigned short* bG = Bt + (size_t)n0 * K;

  const int srow = lane >> 2;
  const int ssl  = (((lane & 3) ^ ((srow >> 1) & 3)) << 3);   // shorts
  const int swA  = (((lane >> 4) ^ ((lane >> 1) & 3)) << 3);  // shorts

  auto stageA = [&](int slot, int kt) {
    #pragma unroll
    for (int j = 0; j < 2; ++j) {
      const int c = wave + j * 8;
      gload_lds16(aG + (size_t)(c * 16 + srow) * K + kt * 32 + ssl,
                  &lds[slot * 8192 + c * 512]);
    }
  };
  auto stageB = [&](int slot, int kt) {
    #pragma unroll
    for (int j = 0; j < 2; ++j) {
      const int c = wave + j * 8;
      gload_lds16(bG + (size_t)(c * 16 + srow) * K + kt * 32 + ssl,
                  &lds[slot * 8192 + c * 512]);
    }
  };

  const int nk = K >> 5;
  stageA(0, 0); stageB(1, 0);
  stageA(2, 1); stageB(3, 1);
  stageA(4, 2); stageB(5, 2);
  asm volatile("s_waitcnt vmcnt(8)" ::: "memory");   // tile 0 landed
  asm volatile("s_barrier" ::: "memory");

  f32x4 acc[8][4] = {};

  for (int kt = 0; kt < nk; ++kt) {
    const int ab = ((2 * kt) & 7) * 8192, bb = ab + 8192;
    const bool more = (kt + 3 < nk);
    bf16x8 af[8], bfr[4];
    // ---- phase 0: reads af[0..3] + bfr[0..3]; issue stage-A(t+3) ----
    #pragma unroll
    for (int mi = 0; mi < 4; ++mi)
      af[mi] = ldb8(&lds[ab + (wm * 128 + mi * 16 + rl15) * 32 + swA]);
    #pragma unroll
    for (int ni = 0; ni < 4; ++ni)
      bfr[ni] = ldb8(&lds[bb + (wn * 64 + ni * 16 + rl15) * 32 + swA]);
    if (more) stageA((2 * (kt + 3)) & 7, kt + 3);
    __builtin_amdgcn_s_barrier();
    asm volatile("s_waitcnt lgkmcnt(0)" ::: "memory");
    __builtin_amdgcn_sched_barrier(0);
    __builtin_amdgcn_s_setprio(1);
    #pragma unroll
    for (int mi = 0; mi < 4; ++mi)
      #pragma unroll
      for (int ni = 0; ni < 4; ++ni)
        acc[mi][ni] = mfma16(af[mi], bfr[ni], acc[mi][ni]);
    __builtin_amdgcn_s_setprio(0);
    __builtin_amdgcn_s_barrier();
    // ---- phase 1: reads af[4..7]; issue stage-B(t+3) ----
    #pragma unroll
    for (int mi = 4; mi < 8; ++mi)
      af[mi] = ldb8(&lds[ab + (wm * 128 + mi * 16 + rl15) * 32 + swA]);
    if (more) stageB(((2 * (kt + 3)) & 7) + 1, kt + 3);
    __builtin_amdgcn_s_barrier();
    asm volatile("s_waitcnt lgkmcnt(0)" ::: "memory");
    __builtin_amdgcn_sched_barrier(0);
    __builtin_amdgcn_s_setprio(1);
    #pragma unroll
    for (int mi = 4; mi < 8; ++mi)
      #pragma unroll
      for (int ni = 0; ni < 4; ++ni)
        acc[mi][ni] = mfma16(af[mi], bfr[ni], acc[mi][ni]);
    __builtin_amdgcn_s_setprio(0);
    if (more)             asm volatile("s_waitcnt vmcnt(8)" ::: "memory");
    else if (kt + 2 < nk) asm volatile("s_waitcnt vmcnt(4)" ::: "memory");
    else                  asm volatile("s_waitcnt vmcnt(0)" ::: "memory");
    asm volatile("s_barrier" ::: "memory");
  }

  const int mrow = m0 + wm * 128 + (lane >> 4) * 4;
  const int ncol = n0 + wn * 64 + rl15;
  #pragma unroll
  for (int ni = 0; ni < 4; ++ni) {
    const int n = ncol + ni * 16;
    const float bn = bias[n];
    #pragma unroll
    for (int mi = 0; mi < 8; ++mi) {
      const int row0 = mrow + mi * 16;
      if constexpr (MODE == 3) {
        if (n >= 2048) {                               // V -> vT[b,h,d,s]
          const int h = (n - 2048) >> 6, d = (n - 2048) & 63;
          const int b = row0 >> 10, s = row0 & 1023;
          ushort4 o;
          o.x = f2bf(acc[mi][ni][0] + bn); o.y = f2bf(acc[mi][ni][1] + bn);
          o.z = f2bf(acc[mi][ni][2] + bn); o.w = f2bf(acc[mi][ni][3] + bn);
          *reinterpret_cast<ushort4*>(vT + ((size_t)(b * 16 + h) * 64 + d) * 1024 + s) = o;
          continue;
        }
      }
      #pragma unroll
      for (int r = 0; r < 4; ++r) {
        const size_t idx = (size_t)(row0 + r) * N + n;
        float v = acc[mi][ni][r] + bn;
        if constexpr (MODE == 1)
          v = 0.5f * v * (1.0f + erff(v * 0.70710678118f));  // exact GELU
        outb[idx] = f2bf(v);
      }
    }
  }
}

// ---------------------------------------------------------------------------
// gemm4k: 128x64 tile, BK=64, 4 waves. 3+3-slot LDS ring (72KB), stage t+2,
// counted vmcnt(6). MODE 2: xout = xin + scl*(C+bias). grid (M/128, N/64).
// ---------------------------------------------------------------------------
template <int MODE>
__global__ __launch_bounds__(256) void gemm4k(
    const unsigned short* __restrict__ A, const unsigned short* __restrict__ Bt,
    const float* __restrict__ bias, unsigned short* __restrict__ outb,
    const float* xin, float* xout, const float* __restrict__ scale_p,
    int N, int K) {
  __shared__ __attribute__((aligned(16))) unsigned short lds[36864]; // 72KB
  const int t = threadIdx.x, wave = t >> 6, lane = t & 63;
  const int m0 = blockIdx.x * 128, n0 = blockIdx.y * 64;
  const int wm = wave >> 1, wn = wave & 1;

  int srowA[4], scolA[4];
  #pragma unroll
  for (int j = 0; j < 4; ++j) {
    const int c = j * 256 + wave * 64 + lane;
    const int r = c >> 3;
    srowA[j] = r;
    scolA[j] = ((c & 7) ^ (r & 7)) << 3;
  }
  const unsigned short* aBase = A + (size_t)m0 * K;
  const unsigned short* bBase = Bt + (size_t)n0 * K;

  const int xk0 = (((lane >> 4)    ) ^ (lane & 7)) << 3;
  const int xk1 = (((lane >> 4) | 4) ^ (lane & 7)) << 3;
  const int arow = (wm * 64 + (lane & 15)) * 64;
  const int brow = (wn * 32 + (lane & 15)) * 64;

  auto stage = [&](int slot, int kt) {
    unsigned short* lA = &lds[slot * 8192];
    unsigned short* lB = &lds[24576 + slot * 4096];
    const int ko = kt * 64;
    #pragma unroll
    for (int j = 0; j < 4; ++j)
      gload_lds16(aBase + (size_t)srowA[j] * K + ko + scolA[j],
                  lA + j * 2048 + wave * 512);
    #pragma unroll
    for (int j = 0; j < 2; ++j)
      gload_lds16(bBase + (size_t)srowA[j] * K + ko + scolA[j],
                  lB + j * 2048 + wave * 512);
  };

  f32x4 acc[4][2] = {};
  const int nk = K >> 6;

  stage(0, 0); stage(1, 1);
  asm volatile("s_waitcnt vmcnt(6)" ::: "memory");
  asm volatile("s_barrier" ::: "memory");

  int cs = 0;
  for (int kt = 0; kt < nk; ++kt) {
    const bool more = (kt + 2 < nk);
    if (more) { int ps = cs + 2; if (ps >= 3) ps -= 3; stage(ps, kt + 2); }
    const unsigned short* lA = &lds[cs * 8192];
    const unsigned short* lB = &lds[24576 + cs * 4096];
    #pragma unroll
    for (int kc = 0; kc < 2; ++kc) {
      const int xk = kc ? xk1 : xk0;
      bf16x8 a[4], b[2];
      #pragma unroll
      for (int mi = 0; mi < 4; ++mi) a[mi] = ldb8(&lA[arow + mi * 1024 + xk]);
      #pragma unroll
      for (int ni = 0; ni < 2; ++ni) b[ni] = ldb8(&lB[brow + ni * 1024 + xk]);
      __builtin_amdgcn_s_setprio(1);
      #pragma unroll
      for (int mi = 0; mi < 4; ++mi)
        #pragma unroll
        for (int ni = 0; ni < 2; ++ni)
          acc[mi][ni] = mfma16(a[mi], b[ni], acc[mi][ni]);
      __builtin_amdgcn_s_setprio(0);
    }
    if (more) asm volatile("s_waitcnt vmcnt(6)" ::: "memory");
    else      asm volatile("s_waitcnt vmcnt(0)" ::: "memory");
    asm volatile("s_barrier" ::: "memory");
    ++cs; if (cs == 3) cs = 0;
  }

  const int mrow = m0 + wm * 64 + (lane >> 4) * 4;
  const int ncol = n0 + wn * 32 + (lane & 15);
  float scl = 0.f;
  if constexpr (MODE == 2) scl = scale_p[0];
  #pragma unroll
  for (int ni = 0; ni < 2; ++ni) {
    const int n = ncol + ni * 16;
    const float bn = bias[n];
    #pragma unroll
    for (int mi = 0; mi < 4; ++mi) {
      #pragma unroll
      for (int r = 0; r < 4; ++r) {
        const size_t idx = (size_t)(mrow + mi * 16 + r) * N + n;
        float v = acc[mi][ni][r] + bn;
        if constexpr (MODE == 2) {
          xout[idx] = xin[idx] + scl * v;      // re-zero residual, fp32
        } else {
          outb[idx] = f2bf(v);
        }
      }
    }
  }
}

// ---------------------------------------------------------------------------
// Flash attention v9: LDS-staged K/V + 32x32x16 MFMA, swapped QK^T and PV.
// grid = 512 (= 8 q-blocks x 64 bh, heavy first), block = 256 (4 waves).
// ---------------------------------------------------------------------------
__global__ __launch_bounds__(256) void attn_kernel(
    const unsigned short* __restrict__ qkv, const unsigned short* __restrict__ vT,
    unsigned short* __restrict__ vals) {
  const int bh = blockIdx.x & 63;
  const int qb = 7 - (blockIdx.x >> 6);       // 7..0, heavy first
  const int b = bh >> 4, h = bh & 15;
  const int t = threadIdx.x, wave = t >> 6, lane = t & 63;
  const int l31 = lane & 31, hi = lane >> 5;
  const int q0w = qb * 128 + wave * 32;
  const int diag = q0w >> 6;                  // wave's diagonal KV64 tile
  const int nkt = qb * 2 + 2;                 // block KV64 tiles

  __shared__ __attribute__((aligned(16))) unsigned short ldsK[2][4096]; // 64x128B
  __shared__ __attribute__((aligned(16))) unsigned short ldsV[2][4096]; // 64x128B

  const unsigned short* qkvB  = qkv + (size_t)b * 1024 * 3072;
  const unsigned short* vHead = vT + (size_t)bh * 64 * 1024;

  const int c0row = t >> 3, c0ch = t & 7;
  const int c1row = (t + 256) >> 3, c1ch = t & 7;
  const int s0col = ((c0ch ^ (c0row & 7)) << 3);
  const int s1col = ((c1ch ^ (c1row & 7)) << 3);
  const int wbase = (t >> 6) * 512;

  auto stageKV = [&](int buf, int kt) {
    const int kv0 = kt * 64;
    gload_lds16(qkvB + (size_t)(kv0 + c0row) * 3072 + 1024 + h * 64 + s0col,
                &ldsK[buf][wbase]);
    gload_lds16(qkvB + (size_t)(kv0 + c1row) * 3072 + 1024 + h * 64 + s1col,
                &ldsK[buf][2048 + wbase]);
    gload_lds16(vHead + (size_t)c0row * 1024 + kv0 + s0col, &ldsV[buf][wbase]);
    gload_lds16(vHead + (size_t)c1row * 1024 + kv0 + s1col, &ldsV[buf][2048 + wbase]);
  };

  const unsigned short* qrow = qkvB + (size_t)(q0w + l31) * 3072 + h * 64 + hi * 8;
  bf16x8 qf[4];
  #pragma unroll
  for (int s = 0; s < 4; ++s) qf[s] = ldb8(qrow + 16 * s);

  f32x16 oacc[2] = {};
  float mrun = -1e30f, lrun = 0.f;

  stageKV(0, 0);
  __syncthreads();

  for (int kt = 0; kt < nkt; ++kt) {
    const int cur = kt & 1;
    if (kt + 1 < nkt) stageKV(cur ^ 1, kt + 1);
    if (kt <= diag) {
      const unsigned short* K = ldsK[cur];
      const unsigned short* V = ldsV[cur];
      #pragma unroll
      for (int sub = 0; sub < 2; ++sub) {
        const int krow = sub * 32 + l31;
        f32x16 sacc = {};
        #pragma unroll
        for (int s = 0; s < 4; ++s) {
          const bf16x8 kf = ldb8(&K[krow * 64 + (((2 * s + hi) ^ (krow & 7)) << 3)]);
          sacc = mfma32(kf, qf[s], sacc);
        }
        float p[16];
        #pragma unroll
        for (int r = 0; r < 16; ++r) p[r] = sacc[r] * 0.125f;
        if (kt == diag) {
          const int qg = q0w + l31;
          #pragma unroll
          for (int r = 0; r < 16; ++r) {
            const int kv = kt * 64 + sub * 32 + (r & 3) + 8 * (r >> 2) + 4 * hi;
            if (kv > qg) p[r] = -1e30f;
          }
        }
        float mloc = p[0];
        #pragma unroll
        for (int r = 1; r < 16; ++r) mloc = fmaxf(mloc, p[r]);
        mloc = fmaxf(mloc, __shfl_xor(mloc, 32));
        const float mnew = fmaxf(mrun, mloc);
        const float facq = __expf(mrun - mnew);
        mrun = mnew;
        float sloc = 0.f;
        #pragma unroll
        for (int r = 0; r < 16; ++r) {
          const float e = __expf(p[r] - mnew);
          p[r] = e;
          sloc += e;
        }
        sloc += __shfl_xor(sloc, 32);
        lrun = lrun * facq + sloc;
        #pragma unroll
        for (int db = 0; db < 2; ++db)
          #pragma unroll
          for (int r = 0; r < 16; ++r) oacc[db][r] *= facq;
        unsigned int w[8], x[8];
        #pragma unroll
        for (int i = 0; i < 8; ++i) w[i] = pack2bf(p[2 * i], p[2 * i + 1]);
        #pragma unroll
        for (int i = 0; i < 8; ++i) x[i] = (unsigned)__shfl_xor((int)w[i], 32);
        #pragma unroll
        for (int ks = 0; ks < 2; ++ks) {
          const int qi = 2 * ks + hi;
          u32x4 fu;
          if (hi) { fu = u32x4{x[2 * qi], x[2 * qi + 1], w[2 * qi], w[2 * qi + 1]}; }
          else    { fu = u32x4{w[2 * qi], w[2 * qi + 1], x[2 * qi], x[2 * qi + 1]}; }
          const bf16x8 pf = __builtin_bit_cast(bf16x8, fu);
          #pragma unroll
          for (int db = 0; db < 2; ++db) {
            const int vrow = db * 32 + l31;
            const int vch  = sub * 4 + ks * 2 + hi;
            const bf16x8 vf = ldb8(&V[vrow * 64 + ((vch ^ (vrow & 7)) << 3)]);
            oacc[db] = mfma32(vf, pf, oacc[db]);
          }
        }
      }
    }
    __syncthreads();
  }

  const float rl = 1.0f / lrun;
  const size_t qrowOut = (size_t)(b * 1024 + q0w + l31) * 1024 + h * 64;
  #pragma unroll
  for (int db = 0; db < 2; ++db)
    #pragma unroll
    for (int rq = 0; rq < 4; ++rq) {
      const int d0 = db * 32 + 8 * rq + 4 * hi;
      ushort4 o;
      o.x = f2bf(oacc[db][rq * 4 + 0] * rl);
      o.y = f2bf(oacc[db][rq * 4 + 1] * rl);
      o.z = f2bf(oacc[db][rq * 4 + 2] * rl);
      o.w = f2bf(oacc[db][rq * 4 + 3] * rl);
      *reinterpret_cast<ushort4*>(vals + qrowOut + d0) = o;
    }
}

// ---------------------------------------------------------------------------
extern "C" void kernel_launch(void* const* d_in, const int* in_sizes, int n_in,
                              void* d_out, int out_size, void* d_ws, size_t ws_size,
                              hipStream_t stream) {
  (void)in_sizes; (void)n_in; (void)out_size; (void)ws_size;
  const float* inputs = (const float*)d_in[0];
  const float* Wq = (const float*)d_in[1];  const float* bq = (const float*)d_in[2];
  const float* Wk = (const float*)d_in[3];  const float* bk = (const float*)d_in[4];
  const float* Wv = (const float*)d_in[5];  const float* bv = (const float*)d_in[6];
  const float* Wo = (const float*)d_in[7];  const float* bo = (const float*)d_in[8];
  const float* W1 = (const float*)d_in[9];  const float* b1 = (const float*)d_in[10];
  const float* W2 = (const float*)d_in[11]; const float* b2 = (const float*)d_in[12];
  const float* ln_g = (const float*)d_in[13];
  const float* ln_b = (const float*)d_in[14];
  const float* scale_p = (const float*)d_in[15];
  float* xbuf = (float*)d_out;               // fp32 residual stream lives here

  char* w = (char*)d_ws;
  size_t off = 0;
  auto take = [&](size_t bytes) {
    void* p = w + off;
    off = (off + bytes + 255) & ~(size_t)255;
    return p;
  };
  unsigned short* Wqkv_t = (unsigned short*)take((size_t)3072 * 1024 * 2);
  unsigned short* Wo_t   = (unsigned short*)take((size_t)1024 * 1024 * 2);
  unsigned short* W1_t   = (unsigned short*)take((size_t)4096 * 1024 * 2);
  unsigned short* W2_t   = (unsigned short*)take((size_t)1024 * 4096 * 2);
  float*          bqkv   = (float*)take(3072 * 4);
  unsigned short* rbuf   = (unsigned short*)take((size_t)4096 * 1024 * 2);
  unsigned short* qkvb   = (unsigned short*)take((size_t)4096 * 3072 * 2);
  unsigned short* vTb    = (unsigned short*)take((size_t)64 * 64 * 1024 * 2);
  unsigned short* valsb  = (unsigned short*)take((size_t)4096 * 1024 * 2);
  unsigned short* hbuf   = (unsigned short*)take((size_t)4096 * 4096 * 2);

  for (int i = 0; i < 8; ++i) {
    const float* xin = (i == 0) ? inputs : xbuf;
    prep_layer<<<12300, 256, 0, stream>>>(
        Wq + (size_t)i * 1024 * 1024, Wk + (size_t)i * 1024 * 1024,
        Wv + (size_t)i * 1024 * 1024, Wo + (size_t)i * 1024 * 1024,
        W1 + (size_t)i * 1024 * 4096, W2 + (size_t)i * 4096 * 1024,
        bq + i * 1024, bk + i * 1024, bv + i * 1024,
        Wqkv_t, Wo_t, W1_t, W2_t, bqkv);
    // attention block
    ln_kernel<0><<<1024, 256, 0, stream>>>(xin, ln_g, ln_b, rbuf);
    gemm8r<3><<<192, 512, 0, stream>>>(rbuf, Wqkv_t, bqkv, qkvb, vTb, 3072, 1024);
    attn_kernel<<<512, 256, 0, stream>>>(qkvb, vTb, valsb);
    gemm4k<2><<<dim3(32, 16), 256, 0, stream>>>(valsb, Wo_t, bo + i * 1024, nullptr,
                                                xin, xbuf, scale_p, 1024, 1024);
    // FFN block
    ln_kernel<0><<<1024, 256, 0, stream>>>(xbuf, ln_g, ln_b, rbuf);
    gemm8r<1><<<256, 512, 0, stream>>>(rbuf, W1_t, b1 + i * 4096, hbuf, nullptr, 4096, 1024);
    gemm4k<2><<<dim3(32, 16), 256, 0, stream>>>(hbuf, W2_t, b2 + i * 1024, nullptr,
                                                xbuf, xbuf, scale_p, 1024, 4096);
  }
  ln_kernel<1><<<1024, 256, 0, stream>>>(xbuf, ln_g, ln_b, xbuf);  // final LN, in-place
}

// Round 18
// 1753.296 us; speedup vs baseline: 1.0087x; 1.0087x over previous
//
#include <hip/hip_runtime.h>

// ---------------------------------------------------------------------------
// Transformer decoder fwd, bf16-MFMA compute, fp32 residual stream in d_out.
// L=8 B=4 S=1024 D=1024 H=16 dh=64 FC=4096. Threshold 0.1 allows bf16 GEMMs.
// QKV/W1: 256^2 ring GEMM (BK=32, 8-slot ring, stage t+3, counted vmcnt(8)).
// Wo/W2: gemm4k (128x64, 3+3-slot ring, vmcnt(6)). LN: wave/row.
// Attn: v9 (LDS-staged K/V, 32x32 MFMA, swapped QK^T/PV, per-lane softmax).
// Weight prep: ONE kernel/layer. (R15-proven configuration, 1755 us.)
// ---------------------------------------------------------------------------

typedef __bf16 bf16x8 __attribute__((ext_vector_type(8)));
typedef float  f32x4  __attribute__((ext_vector_type(4)));
typedef float  f32x16 __attribute__((ext_vector_type(16)));
typedef unsigned int u32x4 __attribute__((ext_vector_type(4)));

#define DEV static __device__ __forceinline__

DEV unsigned short f2bf(float x) {
  unsigned u = __builtin_bit_cast(unsigned int, x);
  u += 0x7fffu + ((u >> 16) & 1u);          // RNE
  return (unsigned short)(u >> 16);
}

DEV unsigned int pack2bf(float lo, float hi) {
  return (unsigned int)f2bf(lo) | ((unsigned int)f2bf(hi) << 16);
}

DEV f32x4 mfma16(bf16x8 a, bf16x8 b, f32x4 c) {
  return __builtin_amdgcn_mfma_f32_16x16x32_bf16(a, b, c, 0, 0, 0);
}

DEV f32x16 mfma32(bf16x8 a, bf16x8 b, f32x16 c) {
  return __builtin_amdgcn_mfma_f32_32x32x16_bf16(a, b, c, 0, 0, 0);
}

DEV bf16x8 ldb8(const unsigned short* p) {
  return *reinterpret_cast<const bf16x8*>(p);
}

DEV void gload_lds16(const unsigned short* g, unsigned short* l) {
  __builtin_amdgcn_global_load_lds(
      (const __attribute__((address_space(1))) void*)g,
      (__attribute__((address_space(3))) void*)l, 16, 0, 0);
}

// ---------------------------------------------------------------------------
// prep_layer: ALL weight prep for one layer in one dispatch.
// ---------------------------------------------------------------------------
__global__ __launch_bounds__(256) void prep_layer(
    const float* __restrict__ Wq, const float* __restrict__ Wk,
    const float* __restrict__ Wv, const float* __restrict__ Wo,
    const float* __restrict__ W1, const float* __restrict__ W2,
    const float* __restrict__ bq, const float* __restrict__ bk,
    const float* __restrict__ bv,
    unsigned short* __restrict__ Wqkv_t, unsigned short* __restrict__ Wo_t,
    unsigned short* __restrict__ W1_t, unsigned short* __restrict__ W2_t,
    float* __restrict__ bqkv) {
  const int bid = blockIdx.x;
  const int t = threadIdx.x;
  if (bid >= 12288) {                        // bias pack (12 x 256 = 3072)
    const int i = (bid - 12288) * 256 + t;
    bqkv[i] = (i < 1024) ? bq[i] : (i < 2048 ? bk[i - 1024] : bv[i - 2048]);
    return;
  }
  const float* src;
  unsigned short* dst;
  int kt, nt, srcStride, dstStride;
  if (bid < 4096) {
    const int z = bid >> 10, tile = bid & 1023;
    src = (z == 0) ? Wq : (z == 1) ? Wk : (z == 2) ? Wv : Wo;
    dst = (z == 3) ? Wo_t : (Wqkv_t + (size_t)z * 1024 * 1024);
    kt = tile >> 5; nt = tile & 31; srcStride = 1024; dstStride = 1024;
  } else if (bid < 8192) {
    const int tile = bid - 4096;
    src = W1; dst = W1_t;
    kt = tile >> 7; nt = tile & 127; srcStride = 4096; dstStride = 1024;
  } else {
    const int tile = bid - 8192;
    src = W2; dst = W2_t;
    kt = tile >> 5; nt = tile & 31; srcStride = 1024; dstStride = 4096;
  }
  __shared__ float ts[32][33];
  const int r = t >> 3, c4 = (t & 7) << 2;
  const int k = kt * 32 + r, n0 = nt * 32 + c4;
  const float4 v = *reinterpret_cast<const float4*>(src + (size_t)k * srcStride + n0);
  ts[r][c4] = v.x; ts[r][c4 + 1] = v.y; ts[r][c4 + 2] = v.z; ts[r][c4 + 3] = v.w;
  __syncthreads();
  const int n = nt * 32 + r, k0 = kt * 32 + c4;
  ushort4 o;
  o.x = f2bf(ts[c4][r]);     o.y = f2bf(ts[c4 + 1][r]);
  o.z = f2bf(ts[c4 + 2][r]); o.w = f2bf(ts[c4 + 3][r]);
  *reinterpret_cast<ushort4*>(dst + (size_t)n * dstStride + k0) = o;
}

// ---------------------------------------------------------------------------
// LayerNorm v2: ONE WAVE PER ROW, 4 rows/block, grid = 1024.
// ---------------------------------------------------------------------------
template <int OUTF32>
__global__ __launch_bounds__(256) void ln_kernel(
    const float* x, const float* __restrict__ gam,
    const float* __restrict__ bet, void* out) {
  const int t = threadIdx.x, wave = t >> 6, lane = t & 63;
  const int row = blockIdx.x * 4 + wave;
  const float* xr = x + (size_t)row * 1024;
  float4 v[4];
  float s = 0.f, ss = 0.f;
  #pragma unroll
  for (int k = 0; k < 4; ++k) {
    v[k] = *reinterpret_cast<const float4*>(xr + k * 256 + lane * 4);
    s  += v[k].x + v[k].y + v[k].z + v[k].w;
    ss += v[k].x * v[k].x + v[k].y * v[k].y + v[k].z * v[k].z + v[k].w * v[k].w;
  }
  #pragma unroll
  for (int m = 1; m <= 32; m <<= 1) { s += __shfl_xor(s, m); ss += __shfl_xor(ss, m); }
  const float mean = s * (1.0f / 1024.0f);
  const float var  = ss * (1.0f / 1024.0f) - mean * mean;
  const float rstd = rsqrtf(var + 1e-5f);
  #pragma unroll
  for (int k = 0; k < 4; ++k) {
    const float4 g  = *reinterpret_cast<const float4*>(gam + k * 256 + lane * 4);
    const float4 bb = *reinterpret_cast<const float4*>(bet + k * 256 + lane * 4);
    const float y0 = (v[k].x - mean) * rstd * g.x + bb.x;
    const float y1 = (v[k].y - mean) * rstd * g.y + bb.y;
    const float y2 = (v[k].z - mean) * rstd * g.z + bb.z;
    const float y3 = (v[k].w - mean) * rstd * g.w + bb.w;
    if (OUTF32) {
      float4 o; o.x = y0; o.y = y1; o.z = y2; o.w = y3;
      *reinterpret_cast<float4*>((float*)out + (size_t)row * 1024 + k * 256 + lane * 4) = o;
    } else {
      ushort4 o; o.x = f2bf(y0); o.y = f2bf(y1); o.z = f2bf(y2); o.w = f2bf(y3);
      *reinterpret_cast<ushort4*>((unsigned short*)out + (size_t)row * 1024 + k * 256 + lane * 4) = o;
    }
  }
}

// ---------------------------------------------------------------------------
// gemm8r: 256x256 tile, BK=32, 512 thr = 8 waves. 8-slot ring (128KB);
// stage t+3; counted vmcnt(8); swizzle slot^=(row>>1)&3.
// MODE 1: bias+gelu. MODE 3: QKV split (V -> vT transposed).
// Ledger: slot of tile t+3 == slot of tile t-1 (mod 8), last read one
// barrier earlier -> WAR-safe. vmcnt(8) leaves t+2,t+3 in flight => t+1 done.
// ---------------------------------------------------------------------------
template <int MODE>
__global__ __launch_bounds__(512) void gemm8r(
    const unsigned short* __restrict__ A, const unsigned short* __restrict__ Bt,
    const float* __restrict__ bias, unsigned short* __restrict__ outb,
    unsigned short* __restrict__ vT, int N, int K) {
  __shared__ __attribute__((aligned(16))) unsigned short lds[8 * 8192]; // 128KB
  const int t = threadIdx.x, wave = t >> 6, lane = t & 63;
  const int wm = wave >> 2, wn = wave & 3;
  const int rl15 = lane & 15;

  const int nbn = N >> 8;
  const int qq  = gridDim.x >> 3;
  const int swz = (blockIdx.x & 7) * qq + (blockIdx.x >> 3);
  const int m0 = (swz / nbn) << 8, n0 = (swz % nbn) << 8;

  const unsigned short* aG = A  + (size_t)m0 * K;
  const unsigned short* bG = Bt + (size_t)n0 * K;

  const int srow = lane >> 2;
  const int ssl  = (((lane & 3) ^ ((srow >> 1) & 3)) << 3);   // shorts
  const int swA  = (((lane >> 4) ^ ((lane >> 1) & 3)) << 3);  // shorts

  auto stageA = [&](int slot, int kt) {
    #pragma unroll
    for (int j = 0; j < 2; ++j) {
      const int c = wave + j * 8;
      gload_lds16(aG + (size_t)(c * 16 + srow) * K + kt * 32 + ssl,
                  &lds[slot * 8192 + c * 512]);
    }
  };
  auto stageB = [&](int slot, int kt) {
    #pragma unroll
    for (int j = 0; j < 2; ++j) {
      const int c = wave + j * 8;
      gload_lds16(bG + (size_t)(c * 16 + srow) * K + kt * 32 + ssl,
                  &lds[slot * 8192 + c * 512]);
    }
  };

  const int nk = K >> 5;
  stageA(0, 0); stageB(1, 0);
  stageA(2, 1); stageB(3, 1);
  stageA(4, 2); stageB(5, 2);
  asm volatile("s_waitcnt vmcnt(8)" ::: "memory");   // tile 0 landed
  asm volatile("s_barrier" ::: "memory");

  f32x4 acc[8][4] = {};

  for (int kt = 0; kt < nk; ++kt) {
    if (kt + 3 < nk) {
      const int p = (2 * (kt + 3)) & 7;
      stageA(p, kt + 3); stageB(p + 1, kt + 3);
    }
    const int ab = ((2 * kt) & 7) * 8192, bb = ab + 8192;
    bf16x8 af[8], bfr[4];
    #pragma unroll
    for (int mi = 0; mi < 8; ++mi)
      af[mi] = ldb8(&lds[ab + (wm * 128 + mi * 16 + rl15) * 32 + swA]);
    #pragma unroll
    for (int ni = 0; ni < 4; ++ni)
      bfr[ni] = ldb8(&lds[bb + (wn * 64 + ni * 16 + rl15) * 32 + swA]);
    __builtin_amdgcn_s_setprio(1);
    #pragma unroll
    for (int mi = 0; mi < 8; ++mi)
      #pragma unroll
      for (int ni = 0; ni < 4; ++ni)
        acc[mi][ni] = mfma16(af[mi], bfr[ni], acc[mi][ni]);
    __builtin_amdgcn_s_setprio(0);
    if (kt + 3 < nk)      asm volatile("s_waitcnt vmcnt(8)" ::: "memory");
    else if (kt + 2 < nk) asm volatile("s_waitcnt vmcnt(4)" ::: "memory");
    else                  asm volatile("s_waitcnt vmcnt(0)" ::: "memory");
    asm volatile("s_barrier" ::: "memory");
  }

  const int mrow = m0 + wm * 128 + (lane >> 4) * 4;
  const int ncol = n0 + wn * 64 + rl15;
  #pragma unroll
  for (int ni = 0; ni < 4; ++ni) {
    const int n = ncol + ni * 16;
    const float bn = bias[n];
    #pragma unroll
    for (int mi = 0; mi < 8; ++mi) {
      const int row0 = mrow + mi * 16;
      if constexpr (MODE == 3) {
        if (n >= 2048) {                               // V -> vT[b,h,d,s]
          const int h = (n - 2048) >> 6, d = (n - 2048) & 63;
          const int b = row0 >> 10, s = row0 & 1023;
          ushort4 o;
          o.x = f2bf(acc[mi][ni][0] + bn); o.y = f2bf(acc[mi][ni][1] + bn);
          o.z = f2bf(acc[mi][ni][2] + bn); o.w = f2bf(acc[mi][ni][3] + bn);
          *reinterpret_cast<ushort4*>(vT + ((size_t)(b * 16 + h) * 64 + d) * 1024 + s) = o;
          continue;
        }
      }
      #pragma unroll
      for (int r = 0; r < 4; ++r) {
        const size_t idx = (size_t)(row0 + r) * N + n;
        float v = acc[mi][ni][r] + bn;
        if constexpr (MODE == 1)
          v = 0.5f * v * (1.0f + erff(v * 0.70710678118f));  // exact GELU
        outb[idx] = f2bf(v);
      }
    }
  }
}

// ---------------------------------------------------------------------------
// gemm4k: 128x64 tile, BK=64, 4 waves. 3+3-slot LDS ring (72KB), stage t+2,
// counted vmcnt(6). MODE 2: xout = xin + scl*(C+bias). grid (M/128, N/64).
// ---------------------------------------------------------------------------
template <int MODE>
__global__ __launch_bounds__(256) void gemm4k(
    const unsigned short* __restrict__ A, const unsigned short* __restrict__ Bt,
    const float* __restrict__ bias, unsigned short* __restrict__ outb,
    const float* xin, float* xout, const float* __restrict__ scale_p,
    int N, int K) {
  __shared__ __attribute__((aligned(16))) unsigned short lds[36864]; // 72KB
  const int t = threadIdx.x, wave = t >> 6, lane = t & 63;
  const int m0 = blockIdx.x * 128, n0 = blockIdx.y * 64;
  const int wm = wave >> 1, wn = wave & 1;

  int srowA[4], scolA[4];
  #pragma unroll
  for (int j = 0; j < 4; ++j) {
    const int c = j * 256 + wave * 64 + lane;
    const int r = c >> 3;
    srowA[j] = r;
    scolA[j] = ((c & 7) ^ (r & 7)) << 3;
  }
  const unsigned short* aBase = A + (size_t)m0 * K;
  const unsigned short* bBase = Bt + (size_t)n0 * K;

  const int xk0 = (((lane >> 4)    ) ^ (lane & 7)) << 3;
  const int xk1 = (((lane >> 4) | 4) ^ (lane & 7)) << 3;
  const int arow = (wm * 64 + (lane & 15)) * 64;
  const int brow = (wn * 32 + (lane & 15)) * 64;

  auto stage = [&](int slot, int kt) {
    unsigned short* lA = &lds[slot * 8192];
    unsigned short* lB = &lds[24576 + slot * 4096];
    const int ko = kt * 64;
    #pragma unroll
    for (int j = 0; j < 4; ++j)
      gload_lds16(aBase + (size_t)srowA[j] * K + ko + scolA[j],
                  lA + j * 2048 + wave * 512);
    #pragma unroll
    for (int j = 0; j < 2; ++j)
      gload_lds16(bBase + (size_t)srowA[j] * K + ko + scolA[j],
                  lB + j * 2048 + wave * 512);
  };

  f32x4 acc[4][2] = {};
  const int nk = K >> 6;

  stage(0, 0); stage(1, 1);
  asm volatile("s_waitcnt vmcnt(6)" ::: "memory");
  asm volatile("s_barrier" ::: "memory");

  int cs = 0;
  for (int kt = 0; kt < nk; ++kt) {
    const bool more = (kt + 2 < nk);
    if (more) { int ps = cs + 2; if (ps >= 3) ps -= 3; stage(ps, kt + 2); }
    const unsigned short* lA = &lds[cs * 8192];
    const unsigned short* lB = &lds[24576 + cs * 4096];
    #pragma unroll
    for (int kc = 0; kc < 2; ++kc) {
      const int xk = kc ? xk1 : xk0;
      bf16x8 a[4], b[2];
      #pragma unroll
      for (int mi = 0; mi < 4; ++mi) a[mi] = ldb8(&lA[arow + mi * 1024 + xk]);
      #pragma unroll
      for (int ni = 0; ni < 2; ++ni) b[ni] = ldb8(&lB[brow + ni * 1024 + xk]);
      __builtin_amdgcn_s_setprio(1);
      #pragma unroll
      for (int mi = 0; mi < 4; ++mi)
        #pragma unroll
        for (int ni = 0; ni < 2; ++ni)
          acc[mi][ni] = mfma16(a[mi], b[ni], acc[mi][ni]);
      __builtin_amdgcn_s_setprio(0);
    }
    if (more) asm volatile("s_waitcnt vmcnt(6)" ::: "memory");
    else      asm volatile("s_waitcnt vmcnt(0)" ::: "memory");
    asm volatile("s_barrier" ::: "memory");
    ++cs; if (cs == 3) cs = 0;
  }

  const int mrow = m0 + wm * 64 + (lane >> 4) * 4;
  const int ncol = n0 + wn * 32 + (lane & 15);
  float scl = 0.f;
  if constexpr (MODE == 2) scl = scale_p[0];
  #pragma unroll
  for (int ni = 0; ni < 2; ++ni) {
    const int n = ncol + ni * 16;
    const float bn = bias[n];
    #pragma unroll
    for (int mi = 0; mi < 4; ++mi) {
      #pragma unroll
      for (int r = 0; r < 4; ++r) {
        const size_t idx = (size_t)(mrow + mi * 16 + r) * N + n;
        float v = acc[mi][ni][r] + bn;
        if constexpr (MODE == 2) {
          xout[idx] = xin[idx] + scl * v;      // re-zero residual, fp32
        } else {
          outb[idx] = f2bf(v);
        }
      }
    }
  }
}

// ---------------------------------------------------------------------------
// Flash attention v9: LDS-staged K/V + 32x32x16 MFMA, swapped QK^T and PV.
// grid = 512 (= 8 q-blocks x 64 bh, heavy first), block = 256 (4 waves).
// ---------------------------------------------------------------------------
__global__ __launch_bounds__(256) void attn_kernel(
    const unsigned short* __restrict__ qkv, const unsigned short* __restrict__ vT,
    unsigned short* __restrict__ vals) {
  const int bh = blockIdx.x & 63;
  const int qb = 7 - (blockIdx.x >> 6);       // 7..0, heavy first
  const int b = bh >> 4, h = bh & 15;
  const int t = threadIdx.x, wave = t >> 6, lane = t & 63;
  const int l31 = lane & 31, hi = lane >> 5;
  const int q0w = qb * 128 + wave * 32;
  const int diag = q0w >> 6;                  // wave's diagonal KV64 tile
  const int nkt = qb * 2 + 2;                 // block KV64 tiles

  __shared__ __attribute__((aligned(16))) unsigned short ldsK[2][4096]; // 64x128B
  __shared__ __attribute__((aligned(16))) unsigned short ldsV[2][4096]; // 64x128B

  const unsigned short* qkvB  = qkv + (size_t)b * 1024 * 3072;
  const unsigned short* vHead = vT + (size_t)bh * 64 * 1024;

  const int c0row = t >> 3, c0ch = t & 7;
  const int c1row = (t + 256) >> 3, c1ch = t & 7;
  const int s0col = ((c0ch ^ (c0row & 7)) << 3);
  const int s1col = ((c1ch ^ (c1row & 7)) << 3);
  const int wbase = (t >> 6) * 512;

  auto stageKV = [&](int buf, int kt) {
    const int kv0 = kt * 64;
    gload_lds16(qkvB + (size_t)(kv0 + c0row) * 3072 + 1024 + h * 64 + s0col,
                &ldsK[buf][wbase]);
    gload_lds16(qkvB + (size_t)(kv0 + c1row) * 3072 + 1024 + h * 64 + s1col,
                &ldsK[buf][2048 + wbase]);
    gload_lds16(vHead + (size_t)c0row * 1024 + kv0 + s0col, &ldsV[buf][wbase]);
    gload_lds16(vHead + (size_t)c1row * 1024 + kv0 + s1col, &ldsV[buf][2048 + wbase]);
  };

  const unsigned short* qrow = qkvB + (size_t)(q0w + l31) * 3072 + h * 64 + hi * 8;
  bf16x8 qf[4];
  #pragma unroll
  for (int s = 0; s < 4; ++s) qf[s] = ldb8(qrow + 16 * s);

  f32x16 oacc[2] = {};
  float mrun = -1e30f, lrun = 0.f;

  stageKV(0, 0);
  __syncthreads();

  for (int kt = 0; kt < nkt; ++kt) {
    const int cur = kt & 1;
    if (kt + 1 < nkt) stageKV(cur ^ 1, kt + 1);
    if (kt <= diag) {
      const unsigned short* K = ldsK[cur];
      const unsigned short* V = ldsV[cur];
      #pragma unroll
      for (int sub = 0; sub < 2; ++sub) {
        const int krow = sub * 32 + l31;
        f32x16 sacc = {};
        #pragma unroll
        for (int s = 0; s < 4; ++s) {
          const bf16x8 kf = ldb8(&K[krow * 64 + (((2 * s + hi) ^ (krow & 7)) << 3)]);
          sacc = mfma32(kf, qf[s], sacc);
        }
        float p[16];
        #pragma unroll
        for (int r = 0; r < 16; ++r) p[r] = sacc[r] * 0.125f;
        if (kt == diag) {
          const int qg = q0w + l31;
          #pragma unroll
          for (int r = 0; r < 16; ++r) {
            const int kv = kt * 64 + sub * 32 + (r & 3) + 8 * (r >> 2) + 4 * hi;
            if (kv > qg) p[r] = -1e30f;
          }
        }
        float mloc = p[0];
        #pragma unroll
        for (int r = 1; r < 16; ++r) mloc = fmaxf(mloc, p[r]);
        mloc = fmaxf(mloc, __shfl_xor(mloc, 32));
        const float mnew = fmaxf(mrun, mloc);
        const float facq = __expf(mrun - mnew);
        mrun = mnew;
        float sloc = 0.f;
        #pragma unroll
        for (int r = 0; r < 16; ++r) {
          const float e = __expf(p[r] - mnew);
          p[r] = e;
          sloc += e;
        }
        sloc += __shfl_xor(sloc, 32);
        lrun = lrun * facq + sloc;
        #pragma unroll
        for (int db = 0; db < 2; ++db)
          #pragma unroll
          for (int r = 0; r < 16; ++r) oacc[db][r] *= facq;
        unsigned int w[8], x[8];
        #pragma unroll
        for (int i = 0; i < 8; ++i) w[i] = pack2bf(p[2 * i], p[2 * i + 1]);
        #pragma unroll
        for (int i = 0; i < 8; ++i) x[i] = (unsigned)__shfl_xor((int)w[i], 32);
        #pragma unroll
        for (int ks = 0; ks < 2; ++ks) {
          const int qi = 2 * ks + hi;
          u32x4 fu;
          if (hi) { fu = u32x4{x[2 * qi], x[2 * qi + 1], w[2 * qi], w[2 * qi + 1]}; }
          else    { fu = u32x4{w[2 * qi], w[2 * qi + 1], x[2 * qi], x[2 * qi + 1]}; }
          const bf16x8 pf = __builtin_bit_cast(bf16x8, fu);
          #pragma unroll
          for (int db = 0; db < 2; ++db) {
            const int vrow = db * 32 + l31;
            const int vch  = sub * 4 + ks * 2 + hi;
            const bf16x8 vf = ldb8(&V[vrow * 64 + ((vch ^ (vrow & 7)) << 3)]);
            oacc[db] = mfma32(vf, pf, oacc[db]);
          }
        }
      }
    }
    __syncthreads();
  }

  const float rl = 1.0f / lrun;
  const size_t qrowOut = (size_t)(b * 1024 + q0w + l31) * 1024 + h * 64;
  #pragma unroll
  for (int db = 0; db < 2; ++db)
    #pragma unroll
    for (int rq = 0; rq < 4; ++rq) {
      const int d0 = db * 32 + 8 * rq + 4 * hi;
      ushort4 o;
      o.x = f2bf(oacc[db][rq * 4 + 0] * rl);
      o.y = f2bf(oacc[db][rq * 4 + 1] * rl);
      o.z = f2bf(oacc[db][rq * 4 + 2] * rl);
      o.w = f2bf(oacc[db][rq * 4 + 3] * rl);
      *reinterpret_cast<ushort4*>(vals + qrowOut + d0) = o;
    }
}

// ---------------------------------------------------------------------------
extern "C" void kernel_launch(void* const* d_in, const int* in_sizes, int n_in,
                              void* d_out, int out_size, void* d_ws, size_t ws_size,
                              hipStream_t stream) {
  (void)in_sizes; (void)n_in; (void)out_size; (void)ws_size;
  const float* inputs = (const float*)d_in[0];
  const float* Wq = (const float*)d_in[1];  const float* bq = (const float*)d_in[2];
  const float* Wk = (const float*)d_in[3];  const float* bk = (const float*)d_in[4];
  const float* Wv = (const float*)d_in[5];  const float* bv = (const float*)d_in[6];
  const float* Wo = (const float*)d_in[7];  const float* bo = (const float*)d_in[8];
  const float* W1 = (const float*)d_in[9];  const float* b1 = (const float*)d_in[10];
  const float* W2 = (const float*)d_in[11]; const float* b2 = (const float*)d_in[12];
  const float* ln_g = (const float*)d_in[13];
  const float* ln_b = (const float*)d_in[14];
  const float* scale_p = (const float*)d_in[15];
  float* xbuf = (float*)d_out;               // fp32 residual stream lives here

  char* w = (char*)d_ws;
  size_t off = 0;
  auto take = [&](size_t bytes) {
    void* p = w + off;
    off = (off + bytes + 255) & ~(size_t)255;
    return p;
  };
  unsigned short* Wqkv_t = (unsigned short*)take((size_t)3072 * 1024 * 2);
  unsigned short* Wo_t   = (unsigned short*)take((size_t)1024 * 1024 * 2);
  unsigned short* W1_t   = (unsigned short*)take((size_t)4096 * 1024 * 2);
  unsigned short* W2_t   = (unsigned short*)take((size_t)1024 * 4096 * 2);
  float*          bqkv   = (float*)take(3072 * 4);
  unsigned short* rbuf   = (unsigned short*)take((size_t)4096 * 1024 * 2);
  unsigned short* qkvb   = (unsigned short*)take((size_t)4096 * 3072 * 2);
  unsigned short* vTb    = (unsigned short*)take((size_t)64 * 64 * 1024 * 2);
  unsigned short* valsb  = (unsigned short*)take((size_t)4096 * 1024 * 2);
  unsigned short* hbuf   = (unsigned short*)take((size_t)4096 * 4096 * 2);

  for (int i = 0; i < 8; ++i) {
    const float* xin = (i == 0) ? inputs : xbuf;
    prep_layer<<<12300, 256, 0, stream>>>(
        Wq + (size_t)i * 1024 * 1024, Wk + (size_t)i * 1024 * 1024,
        Wv + (size_t)i * 1024 * 1024, Wo + (size_t)i * 1024 * 1024,
        W1 + (size_t)i * 1024 * 4096, W2 + (size_t)i * 4096 * 1024,
        bq + i * 1024, bk + i * 1024, bv + i * 1024,
        Wqkv_t, Wo_t, W1_t, W2_t, bqkv);
    // attention block
    ln_kernel<0><<<1024, 256, 0, stream>>>(xin, ln_g, ln_b, rbuf);
    gemm8r<3><<<192, 512, 0, stream>>>(rbuf, Wqkv_t, bqkv, qkvb, vTb, 3072, 1024);
    attn_kernel<<<512, 256, 0, stream>>>(qkvb, vTb, valsb);
    gemm4k<2><<<dim3(32, 16), 256, 0, stream>>>(valsb, Wo_t, bo + i * 1024, nullptr,
                                                xin, xbuf, scale_p, 1024, 1024);
    // FFN block
    ln_kernel<0><<<1024, 256, 0, stream>>>(xbuf, ln_g, ln_b, rbuf);
    gemm8r<1><<<256, 512, 0, stream>>>(rbuf, W1_t, b1 + i * 4096, hbuf, nullptr, 4096, 1024);
    gemm4k<2><<<dim3(32, 16), 256, 0, stream>>>(hbuf, W2_t, b2 + i * 1024, nullptr,
                                                xbuf, xbuf, scale_p, 1024, 4096);
  }
  ln_kernel<1><<<1024, 256, 0, stream>>>(xbuf, ln_g, ln_b, xbuf);  // final LN, in-place
}